// Round 1
// baseline (474.226 us; speedup 1.0000x reference)
//
#include <hip/hip_runtime.h>

// ICNN_net_1503238553972 — round 19: occupancy push. R18 (308us) was
// latency-bound: MfmaUtil 15.5 / VALU 39 / Occupancy 39% / HBM 1%.
// This round halves block granularity: 64 rows/block for BOTH bodies.
//   fhat: H = 64x128 f16 = 16 KB, acc[2][4] (32 f32/lane, was 64).
//   vnet: ILP-1, 16 rows/wave, Z2+Z3 = 4 KB/wave = 16 KB/block.
// LDS 32->16 KB, accumulators halved -> target 6+ blocks/CU (was ~3).
// launch_bounds(256,6). Grid doubles to 15626. prep/combine unchanged.

typedef _Float16 v2h __attribute__((ext_vector_type(2)));
typedef __fp16   v2hf __attribute__((ext_vector_type(2)));
typedef _Float16 v4h __attribute__((ext_vector_type(4)));
typedef _Float16 v8h __attribute__((ext_vector_type(8)));
typedef float    v4f __attribute__((ext_vector_type(4)));

__device__ __forceinline__ v2h cvt_pk(float a, float b){
  v2hf r = __builtin_amdgcn_cvt_pkrtz(a, b);
  union { v2hf f; v2h h; } u; u.f = r;
  return u.h;
}

#define NPTS 500000
#define FH_BLK  ((NPTS + 63) / 64)     // 7813 blocks of 64 rows
#define FUSED_GRID (FH_BLK * 2)        // 15626 (even=fhat, odd=vnet)

// offsets in halves inside g_w16
#define OFF_FW    0               // f2..f5: L*16384, [o*128+k]
#define OFF_V2Z   65536           // [j*64+k]
#define OFF_V3Z   69632
#define OFF_V2ZT  73728           // [k*64+j]
#define OFF_V3ZT  77824
#define OFF_VL1T  81920           // [c*64+j]
#define OFF_V2XT  82048
#define OFF_V3XT  82176
#define OFF_VFZ   82304           // [64]
#define OFF_FFW   82368           // [c*128+k]
#define OFF_F1W   82624           // [oc*2+c]
#define W16_DATA  82880
#define W16_TOTAL (W16_DATA + 2048)   // zero pad: junk A-rows stay in-bounds

__device__ __align__(16) _Float16 g_w16[W16_TOTAL];
__device__ __align__(16) float    g_fh[NPTS * 2];   // f_hat per row (fp32)
__device__ __align__(16) float4   g_grad[NPTS];     // (g0, g1, V, pad)

#if defined(__has_builtin)
#if __has_builtin(__builtin_amdgcn_fdot2)
#define FDOT2(a,b,c) __builtin_amdgcn_fdot2((a),(b),(c),false)
#endif
#endif
#ifndef FDOT2
__device__ __forceinline__ float fdot2_fb(v2h a, v2h b, float c){
  return fmaf((float)a.x, (float)b.x, fmaf((float)a.y, (float)b.y, c));
}
#define FDOT2(a,b,c) fdot2_fb((a),(b),(c))
#endif

__device__ __forceinline__ float srelu(float x){
  float c = fminf(fmaxf(x, 0.f), 1.f);
  return c * fmaf(-0.5f, c, x);
}
__device__ __forceinline__ float sreluD(float x){
  return fminf(fmaxf(x, 0.f), 1.f);
}
__device__ __forceinline__ float sreluD_from_z(float z){
  return fminf(sqrtf(2.f * z), 1.f);
}
__device__ __forceinline__ float dot8(v8h a, v8h b, float s){
  const v2h* ap = (const v2h*)&a;
  const v2h* bp = (const v2h*)&b;
  s = FDOT2(ap[0], bp[0], s);
  s = FDOT2(ap[1], bp[1], s);
  s = FDOT2(ap[2], bp[2], s);
  s = FDOT2(ap[3], bp[3], s);
  return s;
}

// ---- packed f16 activations (2 f32 in -> 2 f16 out) ----
__device__ __forceinline__ v2h lrelu_pk(float a, float b){
  v2h x = cvt_pk(a, b);
  v2h m = x * (v2h){(_Float16)0.01f, (_Float16)0.01f};
  return __builtin_elementwise_max(x, m);
}
__device__ __forceinline__ v2h srelu_pk(float a, float b){
  v2h x = cvt_pk(a, b);
  const v2h z0 = (v2h){(_Float16)0.f, (_Float16)0.f};
  const v2h o1 = (v2h){(_Float16)1.f, (_Float16)1.f};
  const v2h hf = (v2h){(_Float16)0.5f, (_Float16)0.5f};
  v2h c = __builtin_elementwise_min(__builtin_elementwise_max(x, z0), o1);
  v2h t = x - c * hf;
  return c * t;
}

// ---------------- prep: fp32 weights -> f16 layouts (+zero pad) ----------------
__global__ __launch_bounds__(256) void prep_kernel(
  const float* __restrict__ f2w, const float* __restrict__ f3w,
  const float* __restrict__ f4w, const float* __restrict__ f5w,
  const float* __restrict__ V2z, const float* __restrict__ V3z,
  const float* __restrict__ Vl1, const float* __restrict__ V2x,
  const float* __restrict__ V3x, const float* __restrict__ Vfz,
  const float* __restrict__ ffw, const float* __restrict__ f1w)
{
  const int i = blockIdx.x * 256 + threadIdx.x;
  if (i >= W16_TOTAL) return;
  if (i >= W16_DATA){ g_w16[i] = (_Float16)0.f; return; }
  float v;
  if (i < 65536){
    const float* W[4] = {f2w, f3w, f4w, f5w};
    v = W[i >> 14][i & 16383];
  } else if (i < 69632)  v = V2z[i - 65536];
  else if (i < 73728)    v = V3z[i - 69632];
  else if (i < 77824){ int r = i - 73728; v = V2z[(r & 63)*64 + (r >> 6)]; }
  else if (i < 81920){ int r = i - 77824; v = V3z[(r & 63)*64 + (r >> 6)]; }
  else if (i < 82048){ int r = i - 81920; v = Vl1[(r & 63)*2 + (r >> 6)]; }
  else if (i < 82176){ int r = i - 82048; v = V2x[(r & 63)*2 + (r >> 6)]; }
  else if (i < 82304){ int r = i - 82176; v = V3x[(r & 63)*2 + (r >> 6)]; }
  else if (i < 82368)    v = Vfz[i - 82304];
  else if (i < 82624)    v = ffw[i - 82368];
  else                   v = f1w[i - 82624];
  g_w16[i] = (_Float16)v;
}

// ================= fhat block body: 256 thr, 64 rows =================
__device__ __forceinline__ void fh_layer(_Float16* H,
    const _Float16* __restrict__ Wl, const float* __restrict__ Bp,
    int w, int lm, int q)
{
  v4f acc[2][4];
#pragma unroll
  for (int mt = 0; mt < 2; ++mt)
#pragma unroll
    for (int nt = 0; nt < 4; ++nt) acc[mt][nt] = (v4f){0.f,0.f,0.f,0.f};

#pragma unroll
  for (int kt = 0; kt < 4; ++kt){
    const int sw = ((kt*4 + q) ^ lm) << 3;
    v8h A0 = *(const v8h*)(Wl + (w*32      + lm)*128 + kt*32 + q*8);
    v8h A1 = *(const v8h*)(Wl + (w*32 + 16 + lm)*128 + kt*32 + q*8);
#pragma unroll
    for (int nt = 0; nt < 4; ++nt){
      v8h B = *(const v8h*)(H + (nt*16 + lm)*128 + sw);
      acc[0][nt] = __builtin_amdgcn_mfma_f32_16x16x32_f16(A0, B, acc[0][nt], 0,0,0);
      acc[1][nt] = __builtin_amdgcn_mfma_f32_16x16x32_f16(A1, B, acc[1][nt], 0,0,0);
    }
  }
  __syncthreads();
#pragma unroll
  for (int mt = 0; mt < 2; ++mt){
    const int o0 = w*32 + mt*16 + q*4;
    const v4f bv = *(const v4f*)(Bp + o0);
    const int coff = (((o0 >> 3) ^ lm) << 3) + (o0 & 7);
#pragma unroll
    for (int nt = 0; nt < 4; ++nt){
      v4h hv;
      *(v2h*)&hv       = lrelu_pk(acc[mt][nt][0] + bv[0], acc[mt][nt][1] + bv[1]);
      *((v2h*)&hv + 1) = lrelu_pk(acc[mt][nt][2] + bv[2], acc[mt][nt][3] + bv[3]);
      *(v4h*)(H + (nt*16 + lm)*128 + coff) = hv;
    }
  }
  __syncthreads();
}

__device__ __forceinline__ void fhat_body(int b, _Float16* H,
  const float* __restrict__ X,
  const float* __restrict__ f1b, const float* __restrict__ f2b,
  const float* __restrict__ f3b, const float* __restrict__ f4b,
  const float* __restrict__ f5b, const float* __restrict__ ffb)
{
  const int t  = threadIdx.x;
  const int w  = t >> 6;
  const int l  = t & 63;
  const int lm = l & 15;
  const int q  = l >> 4;

  {
    // 4 threads per row, 4 channel-chunks (of 8) each: 64 rows x 128 ch
    const int r = t >> 2, sub = t & 3, rsw = r & 15;
    int g = b*64 + r; if (g > NPTS-1) g = NPTS-1;
    const float2 xv = *(const float2*)(X + g*2);
    v2h xh; xh.x = (_Float16)xv.x; xh.y = (_Float16)xv.y;
#pragma unroll
    for (int c8 = 0; c8 < 4; ++c8){
      const int c = sub*4 + c8;
      const v4f b0 = *(const v4f*)(f1b + c*8);
      const v4f b1 = *(const v4f*)(f1b + c*8 + 4);
      float vv[8];
#pragma unroll
      for (int j = 0; j < 8; ++j){
        const v2h wv = *(const v2h*)(g_w16 + OFF_F1W + (c*8 + j)*2);
        const float bb = (j < 4) ? b0[j] : b1[j-4];
        vv[j] = FDOT2(xh, wv, bb);
      }
      v8h hv;
#pragma unroll
      for (int j2 = 0; j2 < 4; ++j2)
        ((v2h*)&hv)[j2] = lrelu_pk(vv[2*j2], vv[2*j2+1]);
      *(v8h*)(H + r*128 + ((c ^ rsw) << 3)) = hv;
    }
  }
  __syncthreads();

  fh_layer(H, g_w16 + OFF_FW,         f2b, w, lm, q);
  fh_layer(H, g_w16 + OFF_FW + 16384, f3b, w, lm, q);
  fh_layer(H, g_w16 + OFF_FW + 32768, f4b, w, lm, q);
  fh_layer(H, g_w16 + OFF_FW + 49152, f5b, w, lm, q);

  if (t < 128){
    const int r = t >> 1, c = t & 1, rsw = r & 15;
    float s = ffb[c];
    const v8h* wf = (const v8h*)(g_w16 + OFF_FFW + c*128);
#pragma unroll
    for (int ck = 0; ck < 16; ++ck){
      v8h h = *(const v8h*)(H + r*128 + ((ck ^ rsw) << 3));
      s = dot8(h, wf[ck], s);
    }
    const int row = b*64 + r;
    if (row < NPTS) g_fh[row*2 + c] = s;
  }
}

// ================= vnet: ILP-1, 16 rows/wave, 2 arenas =================
// layer-2 fwd: z1 B-fragments built in REGISTERS (no Z1 arena).
__device__ __forceinline__ void vfwd_l2(_Float16* zout,
    const _Float16* __restrict__ Wz,   // V2Z [o][k]
    const _Float16* __restrict__ WxT,  // V2XT [2][64]
    const _Float16* __restrict__ Wl1T, // VL1T [2][64]
    float d0, float d1, int lm, int q)
{
  v4f acc[4];
#pragma unroll
  for (int mt = 0; mt < 4; ++mt) acc[mt] = (v4f){0.f,0.f,0.f,0.f};
  const int rs = lm & 7;
#pragma unroll
  for (int kt = 0; kt < 2; ++kt){
    v8h w0 = *(const v8h*)(Wl1T + kt*32 + q*8);
    v8h w1 = *(const v8h*)(Wl1T + 64 + kt*32 + q*8);
    v8h B;
#pragma unroll
    for (int j2 = 0; j2 < 4; ++j2){
      const float a0 = (float)w0[2*j2  ], a1 = (float)w0[2*j2+1];
      const float c0 = (float)w1[2*j2  ], c1 = (float)w1[2*j2+1];
      ((v2h*)&B)[j2] = srelu_pk(fmaf(d0,a0,d1*c0), fmaf(d0,a1,d1*c1));
    }
#pragma unroll
    for (int mt = 0; mt < 4; ++mt){
      v8h A = *(const v8h*)(Wz + (mt*16 + lm)*64 + kt*32 + q*8);
      acc[mt] = __builtin_amdgcn_mfma_f32_16x16x32_f16(A, B, acc[mt], 0,0,0);
    }
  }
#pragma unroll
  for (int mt = 0; mt < 4; ++mt){
    const int o0 = mt*16 + q*4;
    const int off = (((o0 >> 3) ^ rs) << 3) + (o0 & 7);
    float v[4];
#pragma unroll
    for (int reg = 0; reg < 4; ++reg){
      const float wx0 = (float)WxT[o0 + reg];
      const float wx1 = (float)WxT[64 + o0 + reg];
      v[reg] = acc[mt][reg] + wx0*d0 + wx1*d1;
    }
    v4h h;
    *(v2h*)&h       = srelu_pk(v[0], v[1]);
    *((v2h*)&h + 1) = srelu_pk(v[2], v[3]);
    *(v4h*)(zout + lm*64 + off) = h;
  }
}

// layer-3 fwd (B from LDS)
__device__ __forceinline__ void vfwd(const _Float16* zin, _Float16* zout,
    const _Float16* __restrict__ Wz, const _Float16* __restrict__ WxT,
    float d0, float d1, int lm, int q)
{
  v4f acc[4];
#pragma unroll
  for (int mt = 0; mt < 4; ++mt) acc[mt] = (v4f){0.f,0.f,0.f,0.f};
  const int rs = lm & 7;
#pragma unroll
  for (int kt = 0; kt < 2; ++kt){
    const int sw = (((kt*4 + q) ^ rs) << 3);
    v8h B = *(const v8h*)(zin + lm*64 + sw);
#pragma unroll
    for (int mt = 0; mt < 4; ++mt){
      v8h A = *(const v8h*)(Wz + (mt*16 + lm)*64 + kt*32 + q*8);
      acc[mt] = __builtin_amdgcn_mfma_f32_16x16x32_f16(A, B, acc[mt], 0,0,0);
    }
  }
#pragma unroll
  for (int mt = 0; mt < 4; ++mt){
    const int o0 = mt*16 + q*4;
    const int off = (((o0 >> 3) ^ rs) << 3) + (o0 & 7);
    float v[4];
#pragma unroll
    for (int reg = 0; reg < 4; ++reg){
      const float wx0 = (float)WxT[o0 + reg];
      const float wx1 = (float)WxT[64 + o0 + reg];
      v[reg] = acc[mt][reg] + wx0*d0 + wx1*d1;
    }
    v4h h;
    *(v2h*)&h       = srelu_pk(v[0], v[1]);
    *((v2h*)&h + 1) = srelu_pk(v[2], v[3]);
    *(v4h*)(zout + lm*64 + off) = h;
  }
}

// backward layer-3->2 (srelu' from stored z, in place)
__device__ __forceinline__ void vbwd(const _Float16* gin, _Float16* zio,
    const _Float16* __restrict__ WT, int lm, int q)
{
  v4f acc[4];
#pragma unroll
  for (int mt = 0; mt < 4; ++mt) acc[mt] = (v4f){0.f,0.f,0.f,0.f};
  const int rs = lm & 7;
#pragma unroll
  for (int kt = 0; kt < 2; ++kt){
    const int sw = (((kt*4 + q) ^ rs) << 3);
    v8h B = *(const v8h*)(gin + lm*64 + sw);
#pragma unroll
    for (int mt = 0; mt < 4; ++mt){
      v8h A = *(const v8h*)(WT + (mt*16 + lm)*64 + kt*32 + q*8);
      acc[mt] = __builtin_amdgcn_mfma_f32_16x16x32_f16(A, B, acc[mt], 0,0,0);
    }
  }
#pragma unroll
  for (int mt = 0; mt < 4; ++mt){
    const int k0 = mt*16 + q*4;
    const int off = (((k0 >> 3) ^ rs) << 3) + (k0 & 7);
    _Float16* p = zio + lm*64 + off;
    v4h z = *(const v4h*)p;
    float s0 = acc[mt][0] * sreluD_from_z((float)z[0]);
    float s1 = acc[mt][1] * sreluD_from_z((float)z[1]);
    float s2 = acc[mt][2] * sreluD_from_z((float)z[2]);
    float s3 = acc[mt][3] * sreluD_from_z((float)z[3]);
    v4h gg;
    *(v2h*)&gg       = cvt_pk(s0, s1);
    *((v2h*)&gg + 1) = cvt_pk(s2, s3);
    *(v4h*)p = gg;
  }
}

// backward layer-2->1: srelu'(a1) recomputed exactly; ga1 in place over Z2.
__device__ __forceinline__ void vbwd_l1(_Float16* zio,
    const _Float16* __restrict__ WT,   // V2ZT
    const _Float16* __restrict__ Wl1T, // VL1T [2][64]
    float d0, float d1, int lm, int q)
{
  v4f acc[4];
#pragma unroll
  for (int mt = 0; mt < 4; ++mt) acc[mt] = (v4f){0.f,0.f,0.f,0.f};
  const int rs = lm & 7;
#pragma unroll
  for (int kt = 0; kt < 2; ++kt){
    const int sw = (((kt*4 + q) ^ rs) << 3);
    v8h B = *(const v8h*)(zio + lm*64 + sw);
#pragma unroll
    for (int mt = 0; mt < 4; ++mt){
      v8h A = *(const v8h*)(WT + (mt*16 + lm)*64 + kt*32 + q*8);
      acc[mt] = __builtin_amdgcn_mfma_f32_16x16x32_f16(A, B, acc[mt], 0,0,0);
    }
  }
#pragma unroll
  for (int mt = 0; mt < 4; ++mt){
    const int k0 = mt*16 + q*4;
    const int off = (((k0 >> 3) ^ rs) << 3) + (k0 & 7);
    v4h w0 = *(const v4h*)(Wl1T + k0);
    v4h w1 = *(const v4h*)(Wl1T + 64 + k0);
    float s[4];
#pragma unroll
    for (int reg = 0; reg < 4; ++reg){
      const float a1 = fmaf(d0, (float)w0[reg], d1 * (float)w1[reg]);
      s[reg] = acc[mt][reg] * sreluD(a1);
    }
    v4h gg;
    *(v2h*)&gg       = cvt_pk(s[0], s[1]);
    *((v2h*)&gg + 1) = cvt_pk(s[2], s[3]);
    *(v4h*)(zio + lm*64 + off) = gg;
  }
}

// incremental gradV contribution: aG += WxT-rows MFMA over one arena
__device__ __forceinline__ void gacc(v4f& aG,
    const _Float16* __restrict__ WxTbase,
    const _Float16* Z, int lm, int q)
{
  const int rs = lm & 7;
#pragma unroll
  for (int kt = 0; kt < 2; ++kt){
    const int sw = (((kt*4 + q) ^ rs) << 3);
    v8h A = *(const v8h*)(WxTbase + lm*64 + kt*32 + q*8);
    v8h B = *(const v8h*)(Z + lm*64 + sw);
    aG = __builtin_amdgcn_mfma_f32_16x16x32_f16(A, B, aG, 0,0,0);
  }
}

__device__ __forceinline__ void vnet_body(int b, char* smem,
  const float* __restrict__ X, const float* __restrict__ Xst,
  const float* __restrict__ Vfx)
{
  const int t  = threadIdx.x;
  const int w  = t >> 6;
  const int l  = t & 63;
  const int lm = l & 15;
  const int q  = l >> 4;
  const int rs = lm & 7;

  _Float16* const Z2 = (_Float16*)(smem + w*4096);   // 2 x 2 KB per wave
  _Float16* const Z3 = Z2 + 1024;

  const int row = b*64 + w*16 + lm;
  const int rc  = row < NPTS ? row : NPTS-1;
  const float2 x = *(const float2*)(X   + rc*2);
  const float2 s = *(const float2*)(Xst + rc*2);
  const float d0 = x.x - s.x, d1 = x.y - s.y;
  const float vfx0 = Vfx[0], vfx1 = Vfx[1];

  // fwd: z2 (z1 in registers), z3
  vfwd_l2(Z2, g_w16 + OFF_V2Z, g_w16 + OFF_V2XT, g_w16 + OFF_VL1T,
          d0, d1, lm, q);
  vfwd(Z2, Z3, g_w16 + OFF_V3Z, g_w16 + OFF_V3XT, d0, d1, lm, q);

  // zf head (A row 0 = Vfz)
  float VVr, sf;
  {
    v4f aS = (v4f){0.f,0.f,0.f,0.f};
#pragma unroll
    for (int kt = 0; kt < 2; ++kt){
      const int sw = (((kt*4 + q) ^ rs) << 3);
      v8h A = *(const v8h*)(g_w16 + OFF_VFZ + lm*64 + kt*32 + q*8);
      v8h B = *(const v8h*)(Z3 + lm*64 + sw);
      aS = __builtin_amdgcn_mfma_f32_16x16x32_f16(A, B, aS, 0,0,0);
    }
    const float af = fmaf(vfx0, d0, fmaf(vfx1, d1, aS[0]));
    const float zf = srelu(af);
    VVr = srelu(zf) + 0.01f * fmaf(d0, d0, d1*d1);
    sf  = sreluD(zf) * sreluD(af);
  }

  // u3 = Vfz * srelu'(a3) (sf deferred; in place over Z3)
#pragma unroll
  for (int cc = 0; cc < 2; ++cc){
    const int c = q*2 + cc;
    const int sw = ((c ^ rs) << 3);
    v8h vf = *(const v8h*)(g_w16 + OFF_VFZ + c*8);
    _Float16* p = Z3 + lm*64 + sw;
    v8h z = *(const v8h*)p;
    v8h u;
#pragma unroll
    for (int j2 = 0; j2 < 4; ++j2){
      float a0 = (float)vf[2*j2  ] * sreluD_from_z((float)z[2*j2  ]);
      float a1 = (float)vf[2*j2+1] * sreluD_from_z((float)z[2*j2+1]);
      ((v2h*)&u)[j2] = cvt_pk(a0, a1);
    }
    *(v8h*)p = u;
  }

  // incremental gradV, interleaved with backward (arena reuse)
  v4f aG = (v4f){0.f,0.f,0.f,0.f};

  gacc(aG, g_w16 + OFF_V3XT, Z3, lm, q);                 // L3 (ga3=u3)
  vbwd(Z3, Z2, g_w16 + OFF_V3ZT, lm, q);                 // ga2 -> Z2
  gacc(aG, g_w16 + OFF_V2XT, Z2, lm, q);                 // L2
  vbwd_l1(Z2, g_w16 + OFF_V2ZT, g_w16 + OFF_VL1T,
          d0, d1, lm, q);                                // ga1 -> Z2
  gacc(aG, g_w16 + OFF_VL1T, Z2, lm, q);                 // L1

  const float g0 = fmaf(0.02f, d0, sf * (vfx0 + aG[0]));
  const float g1 = fmaf(0.02f, d1, sf * (vfx1 + aG[1]));

  if (q == 0 && row < NPTS) g_grad[row] = make_float4(g0, g1, VVr, 0.f);
}

// ================= fused heterogeneous kernel =================
__global__ __launch_bounds__(256, 6) void fused_kernel(
  const float* __restrict__ X, const float* __restrict__ Xst,
  const float* __restrict__ Vfx,
  const float* __restrict__ f1b, const float* __restrict__ f2b,
  const float* __restrict__ f3b, const float* __restrict__ f4b,
  const float* __restrict__ f5b, const float* __restrict__ ffb)
{
  __shared__ __align__(16) char smem[16384];   // fhat 16 KB | vnet 16 KB
  const int g = blockIdx.x;
  if ((g & 1) == 0){
    fhat_body(g >> 1, (_Float16*)smem, X, f1b, f2b, f3b, f4b, f5b, ffb);
  } else {
    vnet_body(g >> 1, smem, X, Xst, Vfx);
  }
}

// ================= combine epilogue (2 rows/thread, ~16 MB) =================
__global__ __launch_bounds__(256) void combine_kernel(float* __restrict__ out)
{
  const int idx = blockIdx.x * 256 + threadIdx.x;
  const int i0 = idx * 2;
  if (i0 >= NPTS) return;
  const float4 fh2 = *(const float4*)(g_fh + i0*2);
  const float4 ga = g_grad[i0];
  const float4 gb = g_grad[i0 + 1];
  float4 o;
  {
    const float Vn  = fmaf(ga.x, ga.x, ga.y*ga.y);
    const float num = fmaf(0.1f, ga.z, fmaf(fh2.x, ga.x, fh2.y*ga.y));
    const float fm  = fmaxf(num, 0.f) / (Vn + 1e-10f);
    o.x = fmaf(-ga.x, fm, fh2.x);
    o.y = fmaf(-ga.y, fm, fh2.y);
  }
  {
    const float Vn  = fmaf(gb.x, gb.x, gb.y*gb.y);
    const float num = fmaf(0.1f, gb.z, fmaf(fh2.z, gb.x, fh2.w*gb.y));
    const float fm  = fmaxf(num, 0.f) / (Vn + 1e-10f);
    o.z = fmaf(-gb.x, fm, fh2.z);
    o.w = fmaf(-gb.y, fm, fh2.w);
  }
  *(float4*)(out + i0*2) = o;
}

extern "C" void kernel_launch(void* const* d_in, const int* in_sizes, int n_in,
                              void* d_out, int out_size, void* d_ws, size_t ws_size,
                              hipStream_t stream)
{
  (void)d_ws; (void)ws_size; (void)n_in; (void)in_sizes; (void)out_size;
  const float* X   = (const float*)d_in[0];
  const float* Xst = (const float*)d_in[1];
  const float* Vl1 = (const float*)d_in[2];
  const float* V2x = (const float*)d_in[3];
  const float* V2z = (const float*)d_in[4];
  const float* V3x = (const float*)d_in[5];
  const float* V3z = (const float*)d_in[6];
  const float* Vfx = (const float*)d_in[7];
  const float* Vfz = (const float*)d_in[8];
  const float* f1w = (const float*)d_in[9];
  const float* f1b = (const float*)d_in[10];
  const float* f2w = (const float*)d_in[11];
  const float* f2b = (const float*)d_in[12];
  const float* f3w = (const float*)d_in[13];
  const float* f3b = (const float*)d_in[14];
  const float* f4w = (const float*)d_in[15];
  const float* f4b = (const float*)d_in[16];
  const float* f5w = (const float*)d_in[17];
  const float* f5b = (const float*)d_in[18];
  const float* ffw = (const float*)d_in[19];
  const float* ffb = (const float*)d_in[20];

  prep_kernel<<<(W16_TOTAL + 255)/256, 256, 0, stream>>>(
      f2w, f3w, f4w, f5w, V2z, V3z, Vl1, V2x, V3x, Vfz, ffw, f1w);
  fused_kernel<<<FUSED_GRID, 256, 0, stream>>>(
      X, Xst, Vfx, f1b, f2b, f3b, f4b, f5b, ffb);
  combine_kernel<<<(NPTS/2 + 255)/256, 256, 0, stream>>>((float*)d_out);
}